// Round 6
// baseline (205.848 us; speedup 1.0000x reference)
//
#include <hip/hip_runtime.h>
#include <hip/hip_bf16.h>

typedef __attribute__((ext_vector_type(8))) short bf16x8;
typedef __attribute__((ext_vector_type(4))) float f32x4;
typedef __attribute__((ext_vector_type(4))) short sh4;

static constexpr int NTOK = 8192;   // B*T
static constexpr int D = 1024;
static constexpr int E = 8;
static constexpr int H = 1024;
static constexpr int BM = 128, BN = 128, BK = 32;
static constexpr int NWAVE = NTOK / 64;  // 128 waves over all tokens
static constexpr int NSLOT = 72;         // >= max sum of ceil(cnt_e/BM) = 71

__device__ __forceinline__ unsigned short f2bf(float f) {
  unsigned u = __builtin_bit_cast(unsigned, f);
  u = (u + 0x7FFFu + ((u >> 16) & 1u)) >> 16;   // round-to-nearest-even
  return (unsigned short)u;
}

__device__ __forceinline__ void gload16(const void* g, void* l) {
  __builtin_amdgcn_global_load_lds(
      (const __attribute__((address_space(1))) unsigned int*)g,
      (__attribute__((address_space(3))) unsigned int*)l, 16, 0, 0);
}

// slot -> (expert, m-tile, token offset, count); predicated, no dyn indexing
__device__ __forceinline__ bool tile_map(const int* __restrict__ counts,
                                         int slot, int& e, int& mt,
                                         int& off, int& cnt) {
  int cum = 0, roff = 0;
  bool valid = false;
  e = 0; mt = 0; off = 0; cnt = 0;
#pragma unroll
  for (int i = 0; i < E; ++i) {
    int ci = counts[i];
    int nt = (ci + BM - 1) >> 7;
    bool in = (slot >= cum) & (slot < cum + nt);
    if (in) { e = i; mt = slot - cum; off = roff; cnt = ci; valid = true; }
    cum += nt; roff += ci;
  }
  return valid;
}

// ---------------- router + x->bf16 convert (no atomics) ----------------
__global__ __launch_bounds__(256) void k_router_cvt(
    const float* __restrict__ x, const float* __restrict__ Wg,
    unsigned short* __restrict__ xb, int* __restrict__ sel) {
  __shared__ float wgs[E * D];
  int tid = threadIdx.x;
  const float4* wg4 = (const float4*)Wg;
  float4* ws4 = (float4*)wgs;
  for (int i = tid; i < E * D / 4; i += 256) ws4[i] = wg4[i];
  __syncthreads();
  int lane = tid & 63;
  int t = blockIdx.x * 4 + (tid >> 6);
  const float4* xr = (const float4*)(x + (size_t)t * D);
  unsigned short* xo = xb + (size_t)t * D;
  float acc[E];
#pragma unroll
  for (int e = 0; e < E; ++e) acc[e] = 0.f;
#pragma unroll
  for (int j = 0; j < 4; ++j) {
    int idx = j * 64 + lane;
    float4 v = xr[idx];
    sh4 o;
    o.x = (short)f2bf(v.x); o.y = (short)f2bf(v.y);
    o.z = (short)f2bf(v.z); o.w = (short)f2bf(v.w);
    *(sh4*)(xo + idx * 4) = o;
#pragma unroll
    for (int e = 0; e < E; ++e) {
      float4 wv = *(const float4*)&wgs[e * D + idx * 4];
      acc[e] += v.x * wv.x + v.y * wv.y + v.z * wv.z + v.w * wv.w;
    }
  }
#pragma unroll
  for (int e = 0; e < E; ++e) {
#pragma unroll
    for (int off = 32; off; off >>= 1) acc[e] += __shfl_xor(acc[e], off, 64);
  }
  if (lane == 0) {
    int best = 0; float bv = acc[0];
#pragma unroll
    for (int e = 1; e < E; ++e) if (acc[e] > bv) { bv = acc[e]; best = e; }
    sel[t] = best;
  }
}

// ---------------- per-wave histogram via ballot ----------------
__global__ __launch_bounds__(256) void k_wavecnt(
    const int* __restrict__ sel, int* __restrict__ wcnt) {
  int t = blockIdx.x * 256 + threadIdx.x;
  int lane = threadIdx.x & 63;
  int gwave = t >> 6;
  int s = sel[t];
#pragma unroll
  for (int e = 0; e < E; ++e) {
    unsigned long long m = __ballot(s == e);
    if (lane == 0) wcnt[e * NWAVE + gwave] = __popcll(m);
  }
}

// ---------------- scan: wave bases + counts ----------------
__global__ __launch_bounds__(128) void k_scan(
    const int* __restrict__ wcnt, int* __restrict__ wbase,
    int* __restrict__ counts) {
  __shared__ int cnt[E][NWAVE];
  __shared__ int pre[E][NWAVE];
  __shared__ int eoff[E + 1];
  int tid = threadIdx.x;   // 128 threads
#pragma unroll
  for (int e = 0; e < E; ++e) cnt[e][tid] = wcnt[e * NWAVE + tid];
  __syncthreads();
  if (tid < E) {
    int s = 0;
    for (int w = 0; w < NWAVE; ++w) { pre[tid][w] = s; s += cnt[tid][w]; }
    counts[tid] = s;
  }
  __syncthreads();
  if (tid == 0) {
    int s = 0;
#pragma unroll
    for (int e = 0; e < E; ++e) { eoff[e] = s; s += counts[e]; }
    eoff[E] = s;
  }
  __syncthreads();
#pragma unroll
  for (int e = 0; e < E; ++e) wbase[e * NWAVE + tid] = eoff[e] + pre[e][tid];
}

// ---------------- scatter token list (deterministic) ----------------
__global__ __launch_bounds__(256) void k_scatter(
    const int* __restrict__ sel, const int* __restrict__ wbase,
    int* __restrict__ tlist) {
  int t = blockIdx.x * 256 + threadIdx.x;
  int lane = threadIdx.x & 63;
  int gwave = t >> 6;
  int s = sel[t];
  unsigned long long below = (lane == 63) ? 0x7FFFFFFFFFFFFFFFull
                                          : ((1ull << lane) - 1ull);
  int rank = 0, base = 0;
#pragma unroll
  for (int e = 0; e < E; ++e) {
    unsigned long long m = __ballot(s == e);
    int r = __popcll(m & below);
    int b = wbase[e * NWAVE + gwave];
    rank = (e == s) ? r : rank;
    base = (e == s) ? b : base;
  }
  tlist[base + rank] = t;
}

// ------- weight banks: fp32 [k][n] -> bf16 [n][k] (per 1024x1024 matrix) -------
__global__ __launch_bounds__(256) void k_transpose_banks(
    const float* __restrict__ gate, const float* __restrict__ up,
    const float* __restrict__ down, unsigned short* __restrict__ gt,
    unsigned short* __restrict__ ut, unsigned short* __restrict__ dt) {
  int m = blockIdx.z;
  int mm = m & 7;
  const size_t MS = (size_t)1024 * 1024;
  const float* src;
  unsigned short* dst;
  if (m < 8)       { src = gate + mm * MS; dst = gt + mm * MS; }
  else if (m < 16) { src = up   + mm * MS; dst = ut + mm * MS; }
  else             { src = down + mm * MS; dst = dt + mm * MS; }
  __shared__ unsigned short T[64][72];
  int tid = threadIdx.x;
  int r = tid >> 2;
  int cs = (tid & 3) * 16;
  int tk0 = blockIdx.x * 64, tn0 = blockIdx.y * 64;
  const float* s0 = src + (size_t)(tk0 + r) * 1024 + tn0 + cs;
#pragma unroll
  for (int q = 0; q < 4; ++q) {
    float4 v = *(const float4*)(s0 + q * 4);
    sh4 o;
    o.x = (short)f2bf(v.x); o.y = (short)f2bf(v.y);
    o.z = (short)f2bf(v.z); o.w = (short)f2bf(v.w);
    *(sh4*)&T[r][cs + q * 4] = o;
  }
  __syncthreads();
  unsigned short* d0 = dst + (size_t)(tn0 + r) * 1024 + tk0 + cs;
#pragma unroll
  for (int q = 0; q < 4; ++q) {
    sh4 w;
    w.x = (short)T[cs + q * 4 + 0][r];
    w.y = (short)T[cs + q * 4 + 1][r];
    w.z = (short)T[cs + q * 4 + 2][r];
    w.w = (short)T[cs + q * 4 + 3][r];
    *(sh4*)(d0 + q * 4) = w;
  }
}

// ---------------- grouped GEMM1: h = silu(x@G) * (x@U), bf16 out ----------------
// 2-deep LDS double buffer, counted vmcnt, compacted grid (8 n-tiles x 72 slots).
__global__ __launch_bounds__(256, 3) void k_ffn1(
    const unsigned short* __restrict__ xb, const unsigned short* __restrict__ gt,
    const unsigned short* __restrict__ ut, const int* __restrict__ tlist,
    const int* __restrict__ counts, unsigned short* __restrict__ hbuf) {
  int e, mt, off, cnt;
  if (!tile_map(counts, blockIdx.y, e, mt, off, cnt)) return;
  int rem = cnt - mt * BM;
  if (rem > BM) rem = BM;
  int n0 = blockIdx.x * BN;          // bid%8 = n-tile -> one weight n-slice per XCD
  int tid = threadIdx.x;
  int lane = tid & 63;
  int wid = tid >> 6;
  int wm = wid >> 1, wn = wid & 1;

  __shared__ unsigned short lds[2][12288];   // [buf][ As | Bg | Bu ] (48 KB)

  const unsigned short* gtb = gt + (size_t)e * D * H;
  const unsigned short* utb = ut + (size_t)e * D * H;

  int rr = lane >> 2;
  int skel = 8 * ((lane & 3) ^ (rr & 3) ^ ((rr >> 2) & 3));
  const unsigned short *aP[2], *gP[2], *uP[2];
#pragma unroll
  for (int p = 0; p < 2; ++p) {
    int ch = wid * 2 + p;
    int row = ch * 16 + rr;
    int tr = mt * BM + row; if (tr >= cnt) tr = cnt - 1;   // clamp tail
    int tok = tlist[off + tr];
    aP[p] = xb + (size_t)tok * D + skel;
    gP[p] = gtb + (size_t)(n0 + row) * D + skel;
    uP[p] = utb + (size_t)(n0 + row) * D + skel;
  }

  auto STAGE = [&](int buf, int k0) {
#pragma unroll
    for (int p = 0; p < 2; ++p) {
      int ch = wid * 2 + p;
      unsigned short* base = &lds[buf][ch * 512];
      gload16(aP[p] + k0, base);
      gload16(gP[p] + k0, base + 4096);
      gload16(uP[p] + k0, base + 8192);
    }
  };

  f32x4 accg[4][4], accu[4][4];
#pragma unroll
  for (int m = 0; m < 4; ++m)
#pragma unroll
    for (int n = 0; n < 4; ++n) { accg[m][n] = (f32x4)(0.f); accu[m][n] = (f32x4)(0.f); }

  int fr = lane & 15, s = lane >> 4;
  int swr = 8 * ((s ^ (fr & 3) ^ ((fr >> 2) & 3)) & 3);
  int aoff = (wm * 64 + fr) * 32 + swr;
  int boff = (wn * 64 + fr) * 32 + swr;

  constexpr int NS = D / BK;  // 32
  STAGE(0, 0);
  for (int t = 0; t < NS; ++t) {
    int tn = t + 1; if (tn >= NS) tn = NS - 1;
    STAGE((t + 1) & 1, tn * BK);
    asm volatile("s_waitcnt vmcnt(6)" ::: "memory");
    __builtin_amdgcn_s_barrier();
    asm volatile("" ::: "memory");
    const unsigned short* L = lds[t & 1];
    bf16x8 af[4], bg[4], bu[4];
#pragma unroll
    for (int m = 0; m < 4; ++m) af[m] = *(const bf16x8*)(L + aoff + m * 512);
#pragma unroll
    for (int n = 0; n < 4; ++n) {
      bg[n] = *(const bf16x8*)(L + 4096 + boff + n * 512);
      bu[n] = *(const bf16x8*)(L + 8192 + boff + n * 512);
    }
#pragma unroll
    for (int m = 0; m < 4; ++m)
#pragma unroll
      for (int n = 0; n < 4; ++n) {
        accg[m][n] = __builtin_amdgcn_mfma_f32_16x16x32_bf16(af[m], bg[n], accg[m][n], 0, 0, 0);
        accu[m][n] = __builtin_amdgcn_mfma_f32_16x16x32_bf16(af[m], bu[n], accu[m][n], 0, 0, 0);
      }
    asm volatile("" ::: "memory");
    __builtin_amdgcn_s_barrier();   // reads of buf t&1 done before it's re-staged
  }
  asm volatile("s_waitcnt vmcnt(0)" ::: "memory");

  int gr_base = off + mt * BM;
#pragma unroll
  for (int m = 0; m < 4; ++m) {
#pragma unroll
    for (int j = 0; j < 4; ++j) {
      int r = wm * 64 + m * 16 + s * 4 + j;
      if (r < rem) {
        size_t base = (size_t)(gr_base + r) * H + n0 + wn * 64 + fr;
#pragma unroll
        for (int n = 0; n < 4; ++n) {
          float a = accg[m][n][j];
          float u = accu[m][n][j];
          float hv = (a / (1.f + __expf(-a))) * u;
          hbuf[base + n * 16] = f2bf(hv);
        }
      }
    }
  }
}

// ---------------- grouped GEMM2: y = h @ Dt, scatter fp32 ----------------
__global__ __launch_bounds__(256, 4) void k_ffn2(
    const unsigned short* __restrict__ hbuf, const unsigned short* __restrict__ dt,
    const int* __restrict__ tlist, const int* __restrict__ counts,
    float* __restrict__ y) {
  int e, mt, off, cnt;
  if (!tile_map(counts, blockIdx.y, e, mt, off, cnt)) return;
  int rem = cnt - mt * BM;
  if (rem > BM) rem = BM;
  int n0 = blockIdx.x * BN;
  int tid = threadIdx.x;
  int lane = tid & 63;
  int wid = tid >> 6;
  int wm = wid >> 1, wn = wid & 1;

  __shared__ unsigned short lds[2][8192];   // [buf][ As | Bd ] (32 KB)

  const unsigned short* dtb = dt + (size_t)e * D * H;
  int gr0 = off + mt * BM;

  int rr = lane >> 2;
  int skel = 8 * ((lane & 3) ^ (rr & 3) ^ ((rr >> 2) & 3));
  const unsigned short *aP[2], *dP[2];
#pragma unroll
  for (int p = 0; p < 2; ++p) {
    int ch = wid * 2 + p;
    int row = ch * 16 + rr;
    aP[p] = hbuf + (size_t)(gr0 + row) * H + skel;   // slack rows allocated
    dP[p] = dtb + (size_t)(n0 + row) * H + skel;
  }

  auto STAGE = [&](int buf, int k0) {
#pragma unroll
    for (int p = 0; p < 2; ++p) {
      int ch = wid * 2 + p;
      unsigned short* base = &lds[buf][ch * 512];
      gload16(aP[p] + k0, base);
      gload16(dP[p] + k0, base + 4096);
    }
  };

  f32x4 acc[4][4];
#pragma unroll
  for (int m = 0; m < 4; ++m)
#pragma unroll
    for (int n = 0; n < 4; ++n) acc[m][n] = (f32x4)(0.f);

  int fr = lane & 15, s = lane >> 4;
  int swr = 8 * ((s ^ (fr & 3) ^ ((fr >> 2) & 3)) & 3);
  int aoff = (wm * 64 + fr) * 32 + swr;
  int boff = (wn * 64 + fr) * 32 + swr;

  constexpr int NS = H / BK;  // 32
  STAGE(0, 0);
  for (int t = 0; t < NS; ++t) {
    int tn = t + 1; if (tn >= NS) tn = NS - 1;
    STAGE((t + 1) & 1, tn * BK);
    asm volatile("s_waitcnt vmcnt(4)" ::: "memory");
    __builtin_amdgcn_s_barrier();
    asm volatile("" ::: "memory");
    const unsigned short* L = lds[t & 1];
    bf16x8 af[4], bd[4];
#pragma unroll
    for (int m = 0; m < 4; ++m) af[m] = *(const bf16x8*)(L + aoff + m * 512);
#pragma unroll
    for (int n = 0; n < 4; ++n) bd[n] = *(const bf16x8*)(L + 4096 + boff + n * 512);
#pragma unroll
    for (int m = 0; m < 4; ++m)
#pragma unroll
      for (int n = 0; n < 4; ++n)
        acc[m][n] = __builtin_amdgcn_mfma_f32_16x16x32_bf16(af[m], bd[n], acc[m][n], 0, 0, 0);
    asm volatile("" ::: "memory");
    __builtin_amdgcn_s_barrier();
  }
  asm volatile("s_waitcnt vmcnt(0)" ::: "memory");

#pragma unroll
  for (int m = 0; m < 4; ++m) {
#pragma unroll
    for (int j = 0; j < 4; ++j) {
      int r = wm * 64 + m * 16 + s * 4 + j;
      if (r < rem) {
        int tok = tlist[off + mt * BM + r];
        size_t base = (size_t)tok * D + n0 + wn * 64 + fr;
#pragma unroll
        for (int n = 0; n < 4; ++n) y[base + n * 16] = acc[m][n][j];
      }
    }
  }
}

extern "C" void kernel_launch(void* const* d_in, const int* in_sizes, int n_in,
                              void* d_out, int out_size, void* d_ws, size_t ws_size,
                              hipStream_t stream) {
  const float* x = (const float*)d_in[0];
  const float* Wg = (const float*)d_in[1];
  const float* gate = (const float*)d_in[2];
  const float* up = (const float*)d_in[3];
  const float* down = (const float*)d_in[4];
  float* y = (float*)d_out;

  char* ws = (char*)d_ws;
  int* counts = (int*)ws;                    // 8 ints
  int* sel = (int*)(ws + 1024);              // 8192 ints
  int* wcnt = (int*)(ws + 40960);            // E*NWAVE ints
  int* wbase = (int*)(ws + 45056);           // E*NWAVE ints
  int* tlist = (int*)(ws + 49152);           // 8192 ints
  size_t o = 131072;
  unsigned short* xb = (unsigned short*)(ws + o);  o += (size_t)NTOK * D * 2;
  unsigned short* gt = (unsigned short*)(ws + o);  o += (size_t)E * D * H * 2;
  unsigned short* ut = (unsigned short*)(ws + o);  o += (size_t)E * D * H * 2;
  unsigned short* dt = (unsigned short*)(ws + o);  o += (size_t)E * D * H * 2;
  unsigned short* hbuf = (unsigned short*)(ws + o);  // (NTOK+BM)*H bf16

  k_router_cvt<<<NTOK / 4, 256, 0, stream>>>(x, Wg, xb, sel);
  dim3 gt_grid(16, 16, 24);
  k_transpose_banks<<<gt_grid, 256, 0, stream>>>(gate, up, down, gt, ut, dt);
  k_wavecnt<<<NTOK / 256, 256, 0, stream>>>(sel, wcnt);
  k_scan<<<1, 128, 0, stream>>>(wcnt, wbase, counts);
  k_scatter<<<NTOK / 256, 256, 0, stream>>>(sel, wbase, tlist);
  dim3 gf(8, NSLOT);
  k_ffn1<<<gf, 256, 0, stream>>>(xb, gt, ut, tlist, counts, hbuf);
  k_ffn2<<<gf, 256, 0, stream>>>(hbuf, dt, tlist, counts, y);
}

// Round 7
// 131.484 us; speedup vs baseline: 1.5656x; 1.5656x over previous
//
#include <hip/hip_runtime.h>
#include <hip/hip_bf16.h>

typedef __attribute__((ext_vector_type(8))) short bf16x8;
typedef __attribute__((ext_vector_type(4))) float f32x4;
typedef __attribute__((ext_vector_type(4))) short sh4;

static constexpr int NTOK = 8192;   // B*T
static constexpr int D = 1024;
static constexpr int E = 8;
static constexpr int H = 1024;
static constexpr int BM = 128, BN = 128, BK = 32;
static constexpr int NWAVE = NTOK / 64;  // 128
static constexpr int MSLOT = 24;         // max m-tiles per expert covered (<=3072 tokens)

__device__ __forceinline__ unsigned short f2bf(float f) {
  unsigned u = __builtin_bit_cast(unsigned, f);
  u = (u + 0x7FFFu + ((u >> 16) & 1u)) >> 16;   // round-to-nearest-even
  return (unsigned short)u;
}

__device__ __forceinline__ void gload16(const void* g, void* l) {
  __builtin_amdgcn_global_load_lds(
      (const __attribute__((address_space(1))) unsigned int*)g,
      (__attribute__((address_space(3))) unsigned int*)l, 16, 0, 0);
}

// per-thread prefix over counts (predicated, no dynamic indexing)
__device__ __forceinline__ void expert_span(const int* __restrict__ counts,
                                            int e, int& off, int& cnt) {
  off = 0; cnt = 0;
#pragma unroll
  for (int i = 0; i < E; ++i) {
    int ci = counts[i];
    off += (i < e) ? ci : 0;
    cnt = (i == e) ? ci : cnt;
  }
}

// ---------------- router + x->bf16 convert (no atomics) ----------------
__global__ __launch_bounds__(256) void k_router_cvt(
    const float* __restrict__ x, const float* __restrict__ Wg,
    unsigned short* __restrict__ xb, int* __restrict__ sel) {
  __shared__ float wgs[E * D];
  int tid = threadIdx.x;
  const float4* wg4 = (const float4*)Wg;
  float4* ws4 = (float4*)wgs;
  for (int i = tid; i < E * D / 4; i += 256) ws4[i] = wg4[i];
  __syncthreads();
  int lane = tid & 63;
  int t = blockIdx.x * 4 + (tid >> 6);
  const float4* xr = (const float4*)(x + (size_t)t * D);
  unsigned short* xo = xb + (size_t)t * D;
  float acc[E];
#pragma unroll
  for (int e = 0; e < E; ++e) acc[e] = 0.f;
#pragma unroll
  for (int j = 0; j < 4; ++j) {
    int idx = j * 64 + lane;
    float4 v = xr[idx];
    sh4 o;
    o.x = (short)f2bf(v.x); o.y = (short)f2bf(v.y);
    o.z = (short)f2bf(v.z); o.w = (short)f2bf(v.w);
    *(sh4*)(xo + idx * 4) = o;
#pragma unroll
    for (int e = 0; e < E; ++e) {
      float4 wv = *(const float4*)&wgs[e * D + idx * 4];
      acc[e] += v.x * wv.x + v.y * wv.y + v.z * wv.z + v.w * wv.w;
    }
  }
#pragma unroll
  for (int e = 0; e < E; ++e) {
#pragma unroll
    for (int off = 32; off; off >>= 1) acc[e] += __shfl_xor(acc[e], off, 64);
  }
  if (lane == 0) {
    int best = 0; float bv = acc[0];
#pragma unroll
    for (int e = 1; e < E; ++e) if (acc[e] > bv) { bv = acc[e]; best = e; }
    sel[t] = best;
  }
}

// ---------------- per-wave histogram via ballot ----------------
__global__ __launch_bounds__(256) void k_wavecnt(
    const int* __restrict__ sel, int* __restrict__ wcnt) {
  int t = blockIdx.x * 256 + threadIdx.x;
  int lane = threadIdx.x & 63;
  int gwave = t >> 6;
  int s = sel[t];
#pragma unroll
  for (int e = 0; e < E; ++e) {
    unsigned long long m = __ballot(s == e);
    if (lane == 0) wcnt[e * NWAVE + gwave] = __popcll(m);
  }
}

// ---------------- scan: wave bases + counts ----------------
__global__ __launch_bounds__(128) void k_scan(
    const int* __restrict__ wcnt, int* __restrict__ wbase,
    int* __restrict__ counts) {
  __shared__ int cnt[E][NWAVE];
  __shared__ int pre[E][NWAVE];
  __shared__ int eoff[E + 1];
  int tid = threadIdx.x;   // 128 threads
#pragma unroll
  for (int e = 0; e < E; ++e) cnt[e][tid] = wcnt[e * NWAVE + tid];
  __syncthreads();
  if (tid < E) {
    int s = 0;
    for (int w = 0; w < NWAVE; ++w) { pre[tid][w] = s; s += cnt[tid][w]; }
    counts[tid] = s;
  }
  __syncthreads();
  if (tid == 0) {
    int s = 0;
#pragma unroll
    for (int e = 0; e < E; ++e) { eoff[e] = s; s += counts[e]; }
    eoff[E] = s;
  }
  __syncthreads();
#pragma unroll
  for (int e = 0; e < E; ++e) wbase[e * NWAVE + tid] = eoff[e] + pre[e][tid];
}

// ---------------- scatter token list (deterministic) ----------------
__global__ __launch_bounds__(256) void k_scatter(
    const int* __restrict__ sel, const int* __restrict__ wbase,
    int* __restrict__ tlist) {
  int t = blockIdx.x * 256 + threadIdx.x;
  int lane = threadIdx.x & 63;
  int gwave = t >> 6;
  int s = sel[t];
  unsigned long long below = (lane == 63) ? 0x7FFFFFFFFFFFFFFFull
                                          : ((1ull << lane) - 1ull);
  int rank = 0, base = 0;
#pragma unroll
  for (int e = 0; e < E; ++e) {
    unsigned long long m = __ballot(s == e);
    int r = __popcll(m & below);
    int b = wbase[e * NWAVE + gwave];
    rank = (e == s) ? r : rank;
    base = (e == s) ? b : base;
  }
  tlist[base + rank] = t;
}

// ------- weight banks: fp32 [k][n] -> bf16 [n][k] (per 1024x1024 matrix) -------
__global__ __launch_bounds__(256) void k_transpose_banks(
    const float* __restrict__ gate, const float* __restrict__ up,
    const float* __restrict__ down, unsigned short* __restrict__ gt,
    unsigned short* __restrict__ ut, unsigned short* __restrict__ dt) {
  int m = blockIdx.z;
  int mm = m & 7;
  const size_t MS = (size_t)1024 * 1024;
  const float* src;
  unsigned short* dst;
  if (m < 8)       { src = gate + mm * MS; dst = gt + mm * MS; }
  else if (m < 16) { src = up   + mm * MS; dst = ut + mm * MS; }
  else             { src = down + mm * MS; dst = dt + mm * MS; }
  __shared__ unsigned short T[64][72];
  int tid = threadIdx.x;
  int r = tid >> 2;
  int cs = (tid & 3) * 16;
  int tk0 = blockIdx.x * 64, tn0 = blockIdx.y * 64;
  const float* s0 = src + (size_t)(tk0 + r) * 1024 + tn0 + cs;
#pragma unroll
  for (int q = 0; q < 4; ++q) {
    float4 v = *(const float4*)(s0 + q * 4);
    sh4 o;
    o.x = (short)f2bf(v.x); o.y = (short)f2bf(v.y);
    o.z = (short)f2bf(v.z); o.w = (short)f2bf(v.w);
    *(sh4*)&T[r][cs + q * 4] = o;
  }
  __syncthreads();
  unsigned short* d0 = dst + (size_t)(tn0 + r) * 1024 + tk0 + cs;
#pragma unroll
  for (int q = 0; q < 4; ++q) {
    sh4 w;
    w.x = (short)T[cs + q * 4 + 0][r];
    w.y = (short)T[cs + q * 4 + 1][r];
    w.z = (short)T[cs + q * 4 + 2][r];
    w.w = (short)T[cs + q * 4 + 3][r];
    *(sh4*)(d0 + q * 4) = w;
  }
}

// ---------------- grouped GEMM1: h = silu(x@G) * (x@U), bf16 out ----------------
// 3-deep LDS pipeline (round-4 schedule), XCD = expert (blockIdx.x), L2-resident B.
__global__ __launch_bounds__(256, 2) void k_ffn1(
    const unsigned short* __restrict__ xb, const unsigned short* __restrict__ gt,
    const unsigned short* __restrict__ ut, const int* __restrict__ tlist,
    const int* __restrict__ counts, unsigned short* __restrict__ hbuf) {
  int e = blockIdx.x;                 // linear%8 == blockIdx.x -> XCD = expert
  int mt = blockIdx.y >> 3;
  int n0 = (blockIdx.y & 7) * BN;
  int off, cnt;
  expert_span(counts, e, off, cnt);
  int rem = cnt - mt * BM;
  if (rem <= 0) return;
  if (rem > BM) rem = BM;
  int tid = threadIdx.x;
  int lane = tid & 63;
  int wid = tid >> 6;
  int wm = wid >> 1, wn = wid & 1;

  __shared__ unsigned short lds[3][12288];   // [buf][ As | Bg | Bu ]

  const unsigned short* gtb = gt + (size_t)e * D * H;
  const unsigned short* utb = ut + (size_t)e * D * H;

  int rr = lane >> 2;
  int skel = 8 * ((lane & 3) ^ (rr & 3) ^ ((rr >> 2) & 3));
  const unsigned short *aP[2], *gP[2], *uP[2];
#pragma unroll
  for (int p = 0; p < 2; ++p) {
    int ch = wid * 2 + p;
    int row = ch * 16 + rr;
    int tr = mt * BM + row; if (tr >= cnt) tr = cnt - 1;   // clamp tail
    int tok = tlist[off + tr];
    aP[p] = xb + (size_t)tok * D + skel;
    gP[p] = gtb + (size_t)(n0 + row) * D + skel;
    uP[p] = utb + (size_t)(n0 + row) * D + skel;
  }

  auto STAGE = [&](int buf, int k0) {
#pragma unroll
    for (int p = 0; p < 2; ++p) {
      int ch = wid * 2 + p;
      unsigned short* base = &lds[buf][ch * 512];
      gload16(aP[p] + k0, base);
      gload16(gP[p] + k0, base + 4096);
      gload16(uP[p] + k0, base + 8192);
    }
  };

  f32x4 accg[4][4], accu[4][4];
#pragma unroll
  for (int m = 0; m < 4; ++m)
#pragma unroll
    for (int n = 0; n < 4; ++n) { accg[m][n] = (f32x4)(0.f); accu[m][n] = (f32x4)(0.f); }

  int fr = lane & 15, s = lane >> 4;
  int swr = 8 * ((s ^ (fr & 3) ^ ((fr >> 2) & 3)) & 3);
  int aoff = (wm * 64 + fr) * 32 + swr;
  int boff = (wn * 64 + fr) * 32 + swr;

  constexpr int NS = D / BK;  // 32
  STAGE(0, 0);
  STAGE(1, BK);
  asm volatile("s_waitcnt vmcnt(6)" ::: "memory");
  __builtin_amdgcn_s_barrier();

  int bc = 0, bn_ = 2;
  for (int t = 0; t < NS; ++t) {
    int tn = t + 2; if (tn >= NS) tn = NS - 1;   // clamped prefetch (uniform flow)
    STAGE(bn_, tn * BK);
    const unsigned short* L = lds[bc];
    bf16x8 af[4], bg[4], bu[4];
#pragma unroll
    for (int m = 0; m < 4; ++m) af[m] = *(const bf16x8*)(L + aoff + m * 512);
#pragma unroll
    for (int n = 0; n < 4; ++n) {
      bg[n] = *(const bf16x8*)(L + 4096 + boff + n * 512);
      bu[n] = *(const bf16x8*)(L + 8192 + boff + n * 512);
    }
#pragma unroll
    for (int m = 0; m < 4; ++m)
#pragma unroll
      for (int n = 0; n < 4; ++n) {
        accg[m][n] = __builtin_amdgcn_mfma_f32_16x16x32_bf16(af[m], bg[n], accg[m][n], 0, 0, 0);
        accu[m][n] = __builtin_amdgcn_mfma_f32_16x16x32_bf16(af[m], bu[n], accu[m][n], 0, 0, 0);
      }
    asm volatile("s_waitcnt vmcnt(6)" ::: "memory");
    __builtin_amdgcn_s_barrier();
    bc = (bc == 2) ? 0 : bc + 1;
    bn_ = (bn_ == 2) ? 0 : bn_ + 1;
  }
  asm volatile("s_waitcnt vmcnt(0)" ::: "memory");

  int gr_base = off + mt * BM;
#pragma unroll
  for (int m = 0; m < 4; ++m) {
#pragma unroll
    for (int j = 0; j < 4; ++j) {
      int r = wm * 64 + m * 16 + s * 4 + j;
      if (r < rem) {
        size_t base = (size_t)(gr_base + r) * H + n0 + wn * 64 + fr;
#pragma unroll
        for (int n = 0; n < 4; ++n) {
          float a = accg[m][n][j];
          float u = accu[m][n][j];
          float hv = (a / (1.f + __expf(-a))) * u;
          hbuf[base + n * 16] = f2bf(hv);
        }
      }
    }
  }
}

// ---------------- grouped GEMM2: y = h @ Dt, scatter fp32 ----------------
__global__ __launch_bounds__(256, 2) void k_ffn2(
    const unsigned short* __restrict__ hbuf, const unsigned short* __restrict__ dt,
    const int* __restrict__ tlist, const int* __restrict__ counts,
    float* __restrict__ y) {
  int e = blockIdx.x;
  int mt = blockIdx.y >> 3;
  int n0 = (blockIdx.y & 7) * BN;
  int off, cnt;
  expert_span(counts, e, off, cnt);
  int rem = cnt - mt * BM;
  if (rem <= 0) return;
  if (rem > BM) rem = BM;
  int tid = threadIdx.x;
  int lane = tid & 63;
  int wid = tid >> 6;
  int wm = wid >> 1, wn = wid & 1;

  __shared__ unsigned short lds[3][8192];   // [buf][ As | Bd ]

  const unsigned short* dtb = dt + (size_t)e * D * H;
  int gr0 = off + mt * BM;

  int rr = lane >> 2;
  int skel = 8 * ((lane & 3) ^ (rr & 3) ^ ((rr >> 2) & 3));
  const unsigned short *aP[2], *dP[2];
#pragma unroll
  for (int p = 0; p < 2; ++p) {
    int ch = wid * 2 + p;
    int row = ch * 16 + rr;
    aP[p] = hbuf + (size_t)(gr0 + row) * H + skel;   // slack rows allocated
    dP[p] = dtb + (size_t)(n0 + row) * H + skel;
  }

  auto STAGE = [&](int buf, int k0) {
#pragma unroll
    for (int p = 0; p < 2; ++p) {
      int ch = wid * 2 + p;
      unsigned short* base = &lds[buf][ch * 512];
      gload16(aP[p] + k0, base);
      gload16(dP[p] + k0, base + 4096);
    }
  };

  f32x4 acc[4][4];
#pragma unroll
  for (int m = 0; m < 4; ++m)
#pragma unroll
    for (int n = 0; n < 4; ++n) acc[m][n] = (f32x4)(0.f);

  int fr = lane & 15, s = lane >> 4;
  int swr = 8 * ((s ^ (fr & 3) ^ ((fr >> 2) & 3)) & 3);
  int aoff = (wm * 64 + fr) * 32 + swr;
  int boff = (wn * 64 + fr) * 32 + swr;

  constexpr int NS = H / BK;  // 32
  STAGE(0, 0);
  STAGE(1, BK);
  asm volatile("s_waitcnt vmcnt(4)" ::: "memory");
  __builtin_amdgcn_s_barrier();

  int bc = 0, bn_ = 2;
  for (int t = 0; t < NS; ++t) {
    int tn = t + 2; if (tn >= NS) tn = NS - 1;
    STAGE(bn_, tn * BK);
    const unsigned short* L = lds[bc];
    bf16x8 af[4], bd[4];
#pragma unroll
    for (int m = 0; m < 4; ++m) af[m] = *(const bf16x8*)(L + aoff + m * 512);
#pragma unroll
    for (int n = 0; n < 4; ++n) bd[n] = *(const bf16x8*)(L + 4096 + boff + n * 512);
#pragma unroll
    for (int m = 0; m < 4; ++m)
#pragma unroll
      for (int n = 0; n < 4; ++n)
        acc[m][n] = __builtin_amdgcn_mfma_f32_16x16x32_bf16(af[m], bd[n], acc[m][n], 0, 0, 0);
    asm volatile("s_waitcnt vmcnt(4)" ::: "memory");
    __builtin_amdgcn_s_barrier();
    bc = (bc == 2) ? 0 : bc + 1;
    bn_ = (bn_ == 2) ? 0 : bn_ + 1;
  }
  asm volatile("s_waitcnt vmcnt(0)" ::: "memory");

#pragma unroll
  for (int m = 0; m < 4; ++m) {
#pragma unroll
    for (int j = 0; j < 4; ++j) {
      int r = wm * 64 + m * 16 + s * 4 + j;
      if (r < rem) {
        int tok = tlist[off + mt * BM + r];
        size_t base = (size_t)tok * D + n0 + wn * 64 + fr;
#pragma unroll
        for (int n = 0; n < 4; ++n) y[base + n * 16] = acc[m][n][j];
      }
    }
  }
}

extern "C" void kernel_launch(void* const* d_in, const int* in_sizes, int n_in,
                              void* d_out, int out_size, void* d_ws, size_t ws_size,
                              hipStream_t stream) {
  const float* x = (const float*)d_in[0];
  const float* Wg = (const float*)d_in[1];
  const float* gate = (const float*)d_in[2];
  const float* up = (const float*)d_in[3];
  const float* down = (const float*)d_in[4];
  float* y = (float*)d_out;

  char* ws = (char*)d_ws;
  int* counts = (int*)ws;                    // 8 ints
  int* sel = (int*)(ws + 1024);              // 8192 ints
  int* wcnt = (int*)(ws + 40960);            // E*NWAVE ints
  int* wbase = (int*)(ws + 45056);           // E*NWAVE ints
  int* tlist = (int*)(ws + 49152);           // 8192 ints
  size_t o = 131072;
  unsigned short* xb = (unsigned short*)(ws + o);  o += (size_t)NTOK * D * 2;
  unsigned short* gt = (unsigned short*)(ws + o);  o += (size_t)E * D * H * 2;
  unsigned short* ut = (unsigned short*)(ws + o);  o += (size_t)E * D * H * 2;
  unsigned short* dt = (unsigned short*)(ws + o);  o += (size_t)E * D * H * 2;
  unsigned short* hbuf = (unsigned short*)(ws + o);  // (NTOK+BM)*H bf16

  k_router_cvt<<<NTOK / 4, 256, 0, stream>>>(x, Wg, xb, sel);
  dim3 gt_grid(16, 16, 24);
  k_transpose_banks<<<gt_grid, 256, 0, stream>>>(gate, up, down, gt, ut, dt);
  k_wavecnt<<<NTOK / 256, 256, 0, stream>>>(sel, wcnt);
  k_scan<<<1, 128, 0, stream>>>(wcnt, wbase, counts);
  k_scatter<<<NTOK / 256, 256, 0, stream>>>(sel, wbase, tlist);
  dim3 gf(E, MSLOT * 8);   // x = expert (-> XCD), y = m-tile * 8 + n-tile
  k_ffn1<<<gf, 256, 0, stream>>>(xb, gt, ut, tlist, counts, hbuf);
  k_ffn2<<<gf, 256, 0, stream>>>(hbuf, dt, tlist, counts, y);
}